// Round 1
// baseline (885.216 us; speedup 1.0000x reference)
//
#include <hip/hip_runtime.h>

typedef unsigned short u16;
typedef unsigned int   u32;
typedef u16   u16x8 __attribute__((ext_vector_type(8)));
typedef float f32x4 __attribute__((ext_vector_type(4)));

// ---------- bf16 helpers (bit-level, RNE) ----------
__device__ __forceinline__ float bf2f(u16 u) {
    u32 x = ((u32)u) << 16;
    return __builtin_bit_cast(float, x);
}
__device__ __forceinline__ u16 f2bf(float f) {
    u32 u = __builtin_bit_cast(u32, f);
    u32 r = u + 0x7FFFu + ((u >> 16) & 1u);
    return (u16)(r >> 16);
}

// ---------- sizes ----------
#define TOT   16384      // BS*N nodes
#define HID   512
#define NRELS 8
#define NB    4
#define EDGES 262144
#define INDIM 3072
#define NOUT  128
#define NGRAPH 16
#define NODESPER 1024

// workspace layout (16B aligned)
#define OFF_XB     ((size_t)0)                    // u16 [16384][512]   16,777,216 B
#define OFF_Y      (OFF_XB + 16777216)            // u16 [16384][4096] 134,217,728 B
#define OFF_WCT    (OFF_Y + 134217728)            // u16 [4096][512]     4,194,304 B
#define OFF_WET    (OFF_WCT + 4194304)            // u16 [256][3072]     1,572,864 B
#define OFF_CNT    (OFF_WET + 1572864)            // int [16384]
#define OFF_ROWPTR (OFF_CNT + 65536)              // int [16385] (+pad)
#define OFF_CURSOR (OFF_ROWPTR + 65552)           // int [16384]
#define OFF_EPK    (OFF_CURSOR + 65536)           // int [262144]
#define OFF_ENORM  (OFF_EPK + 1048576)            // float [262144]

// ---------- prep: WcatT[(r*512+n)][k] = sum_b comp[r,b] * V[b][k][n]  (bf16) ----------
__global__ __launch_bounds__(256) void k_prep_wcat(const float* __restrict__ comp,
                                                   const float* __restrict__ V,
                                                   u16* __restrict__ WcatT) {
    int idx = blockIdx.x * 256 + threadIdx.x;      // 8*512*512 = 2,097,152
    int k = idx & 511;
    int n = (idx >> 9) & 511;
    int r = idx >> 18;
    float s = 0.f;
#pragma unroll
    for (int b = 0; b < NB; ++b)
        s = fmaf(comp[r * NB + b], V[((size_t)b << 18) + (size_t)k * 512 + n], s);
    WcatT[(((size_t)(r * 512 + n)) << 9) + k] = f2bf(s);
}

// ---------- prep: WelmoT[n][k] = W_elmo[k][n] (bf16) ----------
__global__ __launch_bounds__(256) void k_prep_welmo(const float* __restrict__ W,
                                                    u16* __restrict__ WT) {
    int idx = blockIdx.x * 256 + threadIdx.x;      // 256*3072 = 786,432
    int k = idx % 3072;
    int n = idx / 3072;
    WT[idx] = f2bf(W[(size_t)k * 256 + n]);
}

// ---------- CSR build ----------
__global__ __launch_bounds__(256) void k_hist(const int* __restrict__ dst, int* __restrict__ cnt) {
    int e = blockIdx.x * 256 + threadIdx.x;
    atomicAdd(&cnt[dst[e]], 1);
}

__global__ __launch_bounds__(1024) void k_scan(const int* __restrict__ cnt,
                                               int* __restrict__ rowptr,
                                               int* __restrict__ cursor) {
    __shared__ int part[1024];
    int t = threadIdx.x;
    int loc[16];
    int s = 0;
    int base = t * 16;
#pragma unroll
    for (int i = 0; i < 16; ++i) { loc[i] = s; s += cnt[base + i]; }
    part[t] = s;
    __syncthreads();
    for (int off = 1; off < 1024; off <<= 1) {
        int v = (t >= off) ? part[t - off] : 0;
        __syncthreads();
        part[t] += v;
        __syncthreads();
    }
    int excl = (t == 0) ? 0 : part[t - 1];
#pragma unroll
    for (int i = 0; i < 16; ++i) {
        int v = excl + loc[i];
        rowptr[base + i] = v;
        cursor[base + i] = v;
    }
    if (t == 1023) rowptr[TOT] = part[1023];
}

__global__ __launch_bounds__(256) void k_scatter(const int* __restrict__ src,
                                                 const int* __restrict__ dst,
                                                 const int* __restrict__ rel,
                                                 const float* __restrict__ norm,
                                                 int* __restrict__ cursor,
                                                 int* __restrict__ epk,
                                                 float* __restrict__ enorm) {
    int e = blockIdx.x * 256 + threadIdx.x;
    int d = dst[e];
    int pos = atomicAdd(&cursor[d], 1);
    epk[pos] = (src[e] << 3) | rel[e];
    enorm[pos] = norm[e];
}

// ---------- bf16 MFMA GEMM: C[M,N](bf16) = op(A[M,K] @ BT[N,K]^T) ----------
// tile 128x128, BK=64, 256 threads (4 waves, 2x2 of 64x64)
template <bool A_IS_F32, bool RELU_BIAS>
__global__ __launch_bounds__(256) void k_gemm(const void* __restrict__ A_,
                                              const u16* __restrict__ BT,
                                              u16* __restrict__ C,
                                              const float* __restrict__ bias,
                                              int K, int lda, int ldc) {
    __shared__ __align__(16) u16 Als[128][72];   // +16B pad -> 4-bank rotation per row
    __shared__ __align__(16) u16 Bls[128][72];

    const int t = threadIdx.x;
    const int tileM = blockIdx.x * 128;
    const int tileN = blockIdx.y * 128;
    const int wave = t >> 6, lane = t & 63;
    const int wr = wave >> 1, wc = wave & 1;
    const int lo = lane & 15, hi = lane >> 4;

    const int srow = t >> 3;         // 0..31
    const int scol = (t & 7) * 8;    // 0,8,..,56 (u16 elements)

    f32x4 acc[4][4];
#pragma unroll
    for (int m = 0; m < 4; ++m)
#pragma unroll
        for (int n = 0; n < 4; ++n) acc[m][n] = f32x4{0.f, 0.f, 0.f, 0.f};

    for (int k0 = 0; k0 < K; k0 += 64) {
        // ---- stage A and B tiles into LDS ----
#pragma unroll
        for (int i = 0; i < 4; ++i) {
            int row = i * 32 + srow;
            if (A_IS_F32) {
                const float* ap = (const float*)A_ + (size_t)(tileM + row) * lda + k0 + scol;
                f32x4 v0 = *(const f32x4*)ap;
                f32x4 v1 = *(const f32x4*)(ap + 4);
                u16x8 w;
#pragma unroll
                for (int j = 0; j < 4; ++j) { w[j] = f2bf(v0[j]); w[j + 4] = f2bf(v1[j]); }
                *(u16x8*)&Als[row][scol] = w;
            } else {
                const u16* ap = (const u16*)A_ + (size_t)(tileM + row) * lda + k0 + scol;
                *(u16x8*)&Als[row][scol] = *(const u16x8*)ap;
            }
            const u16* bp = BT + (size_t)(tileN + row) * K + k0 + scol;
            *(u16x8*)&Bls[row][scol] = *(const u16x8*)bp;
        }
        __syncthreads();

        // ---- fragments + MFMA ----
#pragma unroll
        for (int kk = 0; kk < 2; ++kk) {
            u16x8 af[4], bf[4];
#pragma unroll
            for (int m = 0; m < 4; ++m)
                af[m] = *(const u16x8*)&Als[wr * 64 + m * 16 + lo][kk * 32 + hi * 8];
#pragma unroll
            for (int n = 0; n < 4; ++n)
                bf[n] = *(const u16x8*)&Bls[wc * 64 + n * 16 + lo][kk * 32 + hi * 8];
#pragma unroll
            for (int m = 0; m < 4; ++m)
#pragma unroll
                for (int n = 0; n < 4; ++n)
                    asm volatile("v_mfma_f32_16x16x32_bf16 %0, %1, %2, %0"
                                 : "+v"(acc[m][n])
                                 : "v"(af[m]), "v"(bf[n]));
        }
        __syncthreads();
    }

    // MFMA->VALU hazard fence (inline-asm MFMA bypasses compiler hazard insertion)
    asm volatile("s_nop 7\n\ts_nop 7"
                 : "+v"(acc[0][0]), "+v"(acc[0][1]), "+v"(acc[0][2]), "+v"(acc[0][3]),
                   "+v"(acc[1][0]), "+v"(acc[1][1]), "+v"(acc[1][2]), "+v"(acc[1][3]),
                   "+v"(acc[2][0]), "+v"(acc[2][1]), "+v"(acc[2][2]), "+v"(acc[2][3]),
                   "+v"(acc[3][0]), "+v"(acc[3][1]), "+v"(acc[3][2]), "+v"(acc[3][3]));

    // ---- epilogue: C/D layout col=lane&15, row=(lane>>4)*4+reg ----
#pragma unroll
    for (int m = 0; m < 4; ++m)
#pragma unroll
        for (int n = 0; n < 4; ++n) {
            int col = tileN + wc * 64 + n * 16 + lo;
            float bv = RELU_BIAS ? bias[col] : 0.f;
#pragma unroll
            for (int j = 0; j < 4; ++j) {
                int row = tileM + wr * 64 + m * 16 + hi * 4 + j;
                float v = acc[m][n][j] + bv;
                if (RELU_BIAS) v = fmaxf(v, 0.f);
                C[(size_t)row * ldc + col] = f2bf(v);
            }
        }
}

// ---------- aggregation: x_new[d] = relu(b + sum_e norm_e * y[src_e, r_e*512 + :]) ----------
__global__ __launch_bounds__(512) void k_agg(const u16* __restrict__ y,
                                             const int* __restrict__ rowptr,
                                             const int* __restrict__ epk,
                                             const float* __restrict__ enorm,
                                             const float* __restrict__ bgcn,
                                             u16* __restrict__ xout) {
    int d = blockIdx.x, t = threadIdx.x;
    float acc = bgcn[t];
    int beg = rowptr[d], end = rowptr[d + 1];
    for (int p = beg; p < end; ++p) {
        int sr = epk[p];
        float nm = enorm[p];
        acc = fmaf(nm, bf2f(y[((size_t)(sr >> 3) << 12) + (size_t)((sr & 7) << 9) + t]), acc);
    }
    xout[((size_t)d << 9) + t] = f2bf(fmaxf(acc, 0.f));
}

// ---------- final: per-graph mean -> logits -> softmax ----------
__global__ __launch_bounds__(512) void k_final(const u16* __restrict__ xb,
                                               const float* __restrict__ W_out,
                                               const float* __restrict__ b_out,
                                               float* __restrict__ out) {
    int g = blockIdx.x, t = threadIdx.x;
    __shared__ float mean_s[512];
    __shared__ float lg[128];
    __shared__ float red[128];
    const u16* base = xb + (size_t)g * NODESPER * HID;
    float s = 0.f;
    for (int n = 0; n < NODESPER; ++n) s += bf2f(base[(size_t)n * HID + t]);
    mean_s[t] = s * (1.0f / (float)NODESPER);
    __syncthreads();
    if (t < NOUT) {
        float a = b_out[t];
        for (int k = 0; k < HID; ++k) a = fmaf(mean_s[k], W_out[(size_t)k * NOUT + t], a);
        lg[t] = a;
        red[t] = a;
    }
    __syncthreads();
    for (int off = 64; off > 0; off >>= 1) {
        if (t < off) red[t] = fmaxf(red[t], red[t + off]);
        __syncthreads();
    }
    float mx = red[0];
    __syncthreads();
    if (t < NOUT) { float e = expf(lg[t] - mx); lg[t] = e; red[t] = e; }
    __syncthreads();
    for (int off = 64; off > 0; off >>= 1) {
        if (t < off) red[t] += red[t + off];
        __syncthreads();
    }
    if (t < NOUT) out[(size_t)g * NOUT + t] = lg[t] / red[0];
}

extern "C" void kernel_launch(void* const* d_in, const int* in_sizes, int n_in,
                              void* d_out, int out_size, void* d_ws, size_t ws_size,
                              hipStream_t stream) {
    const float* h      = (const float*)d_in[0];
    const int*   src    = (const int*)d_in[1];
    const int*   dst    = (const int*)d_in[2];
    const int*   rel    = (const int*)d_in[3];
    const float* norm   = (const float*)d_in[4];
    const float* W_elmo = (const float*)d_in[5];
    const float* b_elmo = (const float*)d_in[6];
    const float* comp   = (const float*)d_in[7];
    const float* V      = (const float*)d_in[8];
    const float* b_gcn  = (const float*)d_in[9];
    const float* W_out  = (const float*)d_in[10];
    const float* b_out  = (const float*)d_in[11];
    float* out = (float*)d_out;

    char* ws = (char*)d_ws;
    u16*   xb     = (u16*)(ws + OFF_XB);
    u16*   y      = (u16*)(ws + OFF_Y);
    u16*   wcatT  = (u16*)(ws + OFF_WCT);
    u16*   welmoT = (u16*)(ws + OFF_WET);
    int*   cnt    = (int*)(ws + OFF_CNT);
    int*   rowptr = (int*)(ws + OFF_ROWPTR);
    int*   cursor = (int*)(ws + OFF_CURSOR);
    int*   epk    = (int*)(ws + OFF_EPK);
    float* enorm  = (float*)(ws + OFF_ENORM);

    // zero x buffer (upper 256 feature dims stay 0 for layer-1 input) and histogram
    hipMemsetAsync(xb, 0, (size_t)TOT * HID * 2, stream);
    hipMemsetAsync(cnt, 0, (size_t)TOT * 4, stream);

    k_prep_wcat<<<8192, 256, 0, stream>>>(comp, V, wcatT);
    k_prep_welmo<<<3072, 256, 0, stream>>>(W_elmo, welmoT);

    k_hist<<<EDGES / 256, 256, 0, stream>>>(dst, cnt);
    k_scan<<<1, 1024, 0, stream>>>(cnt, rowptr, cursor);
    k_scatter<<<EDGES / 256, 256, 0, stream>>>(src, dst, rel, norm, cursor, epk, enorm);

    // ELMo: xb[:, 0:256] = relu(h @ W_elmo + b_elmo)   (M=16384, K=3072, N=256)
    k_gemm<true, true><<<dim3(128, 2), 256, 0, stream>>>(h, welmoT, xb, b_elmo,
                                                         INDIM, INDIM, HID);

    for (int L = 0; L < 3; ++L) {
        // y = xb @ Wcat   (M=16384, K=512, N=4096)
        k_gemm<false, false><<<dim3(128, 32), 256, 0, stream>>>(xb, wcatT, y, nullptr,
                                                                HID, HID, NRELS * HID);
        // xb = relu(b_gcn + segment_sum(norm * y[src, r]))
        k_agg<<<TOT, 512, 0, stream>>>(y, rowptr, epk, enorm, b_gcn, xb);
    }

    k_final<<<NGRAPH, 512, 0, stream>>>(xb, W_out, b_out, out);
}

// Round 2
// 786.090 us; speedup vs baseline: 1.1261x; 1.1261x over previous
//
#include <hip/hip_runtime.h>

typedef unsigned short u16;
typedef unsigned int   u32;
typedef u16   u16x8 __attribute__((ext_vector_type(8)));
typedef short s16x8 __attribute__((ext_vector_type(8)));
typedef float f32x4 __attribute__((ext_vector_type(4)));

// ---------- bf16 helpers (bit-level, RNE) ----------
__device__ __forceinline__ float bf2f(u16 u) {
    u32 x = ((u32)u) << 16;
    return __builtin_bit_cast(float, x);
}
__device__ __forceinline__ u16 f2bf(float f) {
    u32 u = __builtin_bit_cast(u32, f);
    u32 r = u + 0x7FFFu + ((u >> 16) & 1u);
    return (u16)(r >> 16);
}

// async global->LDS, 16B per lane; lds dest must be wave-uniform base (HW: base + lane*16)
__device__ __forceinline__ void gload16(const u16* g, u16* lds) {
    __builtin_amdgcn_global_load_lds((const __attribute__((address_space(1))) void*)g,
                                     (__attribute__((address_space(3))) void*)lds, 16, 0, 0);
}

// ---------- sizes ----------
#define TOT   16384      // BS*N nodes
#define HID   512
#define NRELS 8
#define NB    4
#define EDGES 262144
#define INDIM 3072
#define NOUT  128
#define NGRAPH 16
#define NODESPER 1024

// workspace layout (16B aligned)
#define OFF_XB     ((size_t)0)                    // u16 [16384][512]   16,777,216 B
#define OFF_Y      (OFF_XB + 16777216)            // u16 [16384][4096] 134,217,728 B  (also reused as hbf [16384][3072] = 100,663,296 B)
#define OFF_WCT    (OFF_Y + 134217728)            // u16 [4096][512]     4,194,304 B
#define OFF_WET    (OFF_WCT + 4194304)            // u16 [256][3072]     1,572,864 B
#define OFF_CNT    (OFF_WET + 1572864)            // int [16384]
#define OFF_ROWPTR (OFF_CNT + 65536)              // int [16385] (+pad)
#define OFF_CURSOR (OFF_ROWPTR + 65552)           // int [16384]
#define OFF_EPK    (OFF_CURSOR + 65536)           // int [262144]
#define OFF_ENORM  (OFF_EPK + 1048576)            // float [262144]

// ---------- h (f32) -> bf16, vectorized ----------
__global__ __launch_bounds__(256) void k_cvt(const float* __restrict__ in,
                                             u16* __restrict__ o) {
    const int n8 = (TOT * INDIM) / 8;  // 6,291,456 groups of 8
    for (int i = blockIdx.x * 256 + threadIdx.x; i < n8; i += 2048 * 256) {
        const f32x4* p = (const f32x4*)(in + (size_t)i * 8);
        f32x4 v0 = p[0], v1 = p[1];
        u16x8 wv;
#pragma unroll
        for (int j = 0; j < 4; ++j) { wv[j] = f2bf(v0[j]); wv[j + 4] = f2bf(v1[j]); }
        *(u16x8*)(o + (size_t)i * 8) = wv;
    }
}

// ---------- prep: WcatT[(r*512+n)][k] = sum_b comp[r,b] * V[b][k][n]  (bf16) ----------
__global__ __launch_bounds__(256) void k_prep_wcat(const float* __restrict__ comp,
                                                   const float* __restrict__ V,
                                                   u16* __restrict__ WcatT) {
    int idx = blockIdx.x * 256 + threadIdx.x;      // 8*512*512 = 2,097,152
    int k = idx & 511;
    int n = (idx >> 9) & 511;
    int r = idx >> 18;
    float s = 0.f;
#pragma unroll
    for (int b = 0; b < NB; ++b)
        s = fmaf(comp[r * NB + b], V[((size_t)b << 18) + (size_t)k * 512 + n], s);
    WcatT[(((size_t)(r * 512 + n)) << 9) + k] = f2bf(s);
}

// ---------- prep: WelmoT[n][k] = W_elmo[k][n] (bf16) ----------
__global__ __launch_bounds__(256) void k_prep_welmo(const float* __restrict__ W,
                                                    u16* __restrict__ WT) {
    int idx = blockIdx.x * 256 + threadIdx.x;      // 256*3072 = 786,432
    int k = idx % 3072;
    int n = idx / 3072;
    WT[idx] = f2bf(W[(size_t)k * 256 + n]);
}

// ---------- CSR build ----------
__global__ __launch_bounds__(256) void k_hist(const int* __restrict__ dst, int* __restrict__ cnt) {
    int e = blockIdx.x * 256 + threadIdx.x;
    atomicAdd(&cnt[dst[e]], 1);
}

__global__ __launch_bounds__(1024) void k_scan(const int* __restrict__ cnt,
                                               int* __restrict__ rowptr,
                                               int* __restrict__ cursor) {
    __shared__ int part[1024];
    int t = threadIdx.x;
    int loc[16];
    int s = 0;
    int base = t * 16;
#pragma unroll
    for (int i = 0; i < 16; ++i) { loc[i] = s; s += cnt[base + i]; }
    part[t] = s;
    __syncthreads();
    for (int off = 1; off < 1024; off <<= 1) {
        int v = (t >= off) ? part[t - off] : 0;
        __syncthreads();
        part[t] += v;
        __syncthreads();
    }
    int excl = (t == 0) ? 0 : part[t - 1];
#pragma unroll
    for (int i = 0; i < 16; ++i) {
        int v = excl + loc[i];
        rowptr[base + i] = v;
        cursor[base + i] = v;
    }
    if (t == 1023) rowptr[TOT] = part[1023];
}

__global__ __launch_bounds__(256) void k_scatter(const int* __restrict__ src,
                                                 const int* __restrict__ dst,
                                                 const int* __restrict__ rel,
                                                 const float* __restrict__ norm,
                                                 int* __restrict__ cursor,
                                                 int* __restrict__ epk,
                                                 float* __restrict__ enorm) {
    int e = blockIdx.x * 256 + threadIdx.x;
    int d = dst[e];
    int pos = atomicAdd(&cursor[d], 1);
    epk[pos] = (src[e] << 3) | rel[e];
    enorm[pos] = norm[e];
}

// ---------- bf16 MFMA GEMM (m97 structure): C[M,N](bf16) = op(A[M,K] @ BT[N,K]^T) ----------
// tile 128x128, BK=64, 256 threads (4 waves, 2x2 of 64x64 sub-tiles)
// LDS linear [128][64] u16 per operand; global_load_lds width-16 staging with
// both-sides XOR swizzle (source chunk (l&7)^(l>>3), read byte ^ ((row&7)<<4))
// -> conflict-free ds_read_b128.
template <bool RELU_BIAS>
__global__ __launch_bounds__(256, 4) void k_gemm(const u16* __restrict__ A,
                                                 const u16* __restrict__ BT,
                                                 u16* __restrict__ C,
                                                 const float* __restrict__ bias,
                                                 int K, int ldc) {
    __shared__ __align__(16) u16 As[128 * 64];
    __shared__ __align__(16) u16 Bs[128 * 64];

    const int t = threadIdx.x;
    const int tileM = blockIdx.x * 128;
    const int tileN = blockIdx.y * 128;
    const int w = t >> 6, l = t & 63;
    const int wr = w >> 1, wc = w & 1;
    const int lo = l & 15, hi = l >> 4;

    const int srow8 = l >> 3;                 // 0..7: row within 8-row staging group
    const int scol = ((l & 7) ^ srow8) * 8;   // swizzled source 16B-chunk (u16 units)

    f32x4 acc[4][4];
#pragma unroll
    for (int m = 0; m < 4; ++m)
#pragma unroll
        for (int n = 0; n < 4; ++n) acc[m][n] = f32x4{0.f, 0.f, 0.f, 0.f};

    for (int k0 = 0; k0 < K; k0 += 64) {
        // ---- stage A and B tiles (8 x global_load_lds_dwordx4 per wave) ----
#pragma unroll
        for (int i = 0; i < 4; ++i) {
            const int rowblk = (w * 4 + i) * 8;            // wave-uniform
            const u16* ga = A + (size_t)(tileM + rowblk + srow8) * K + k0 + scol;
            gload16(ga, &As[rowblk * 64]);
            const u16* gb = BT + (size_t)(tileN + rowblk + srow8) * K + k0 + scol;
            gload16(gb, &Bs[rowblk * 64]);
        }
        __syncthreads();   // compiler emits s_waitcnt vmcnt(0) before s_barrier

        // ---- fragments (swizzled read) + MFMA ----
#pragma unroll
        for (int kk = 0; kk < 2; ++kk) {
            s16x8 af[4], bf[4];
#pragma unroll
            for (int m = 0; m < 4; ++m) {
                int row = wr * 64 + m * 16 + lo;
                int boff = (row * 128 + kk * 64 + hi * 16) ^ ((row & 7) << 4);
                af[m] = *(const s16x8*)((const char*)As + boff);
            }
#pragma unroll
            for (int n = 0; n < 4; ++n) {
                int row = wc * 64 + n * 16 + lo;
                int boff = (row * 128 + kk * 64 + hi * 16) ^ ((row & 7) << 4);
                bf[n] = *(const s16x8*)((const char*)Bs + boff);
            }
#pragma unroll
            for (int m = 0; m < 4; ++m)
#pragma unroll
                for (int n = 0; n < 4; ++n)
                    acc[m][n] = __builtin_amdgcn_mfma_f32_16x16x32_bf16(
                        af[m], bf[n], acc[m][n], 0, 0, 0);
        }
        __syncthreads();
    }

    // ---- epilogue: C/D layout col=lane&15, row=(lane>>4)*4+reg ----
#pragma unroll
    for (int m = 0; m < 4; ++m)
#pragma unroll
        for (int n = 0; n < 4; ++n) {
            int col = tileN + wc * 64 + n * 16 + lo;
            float bv = RELU_BIAS ? bias[col] : 0.f;
#pragma unroll
            for (int j = 0; j < 4; ++j) {
                int row = tileM + wr * 64 + m * 16 + hi * 4 + j;
                float v = acc[m][n][j] + bv;
                if (RELU_BIAS) v = fmaxf(v, 0.f);
                C[(size_t)row * ldc + col] = f2bf(v);
            }
        }
}

// ---------- aggregation: x_new[d] = relu(b + sum_e norm_e * y[src_e, r_e*512 + :]) ----------
__global__ __launch_bounds__(512) void k_agg(const u16* __restrict__ y,
                                             const int* __restrict__ rowptr,
                                             const int* __restrict__ epk,
                                             const float* __restrict__ enorm,
                                             const float* __restrict__ bgcn,
                                             u16* __restrict__ xout) {
    int d = blockIdx.x, t = threadIdx.x;
    float acc = bgcn[t];
    int beg = rowptr[d], end = rowptr[d + 1];
    for (int p = beg; p < end; ++p) {
        int sr = epk[p];
        float nm = enorm[p];
        acc = fmaf(nm, bf2f(y[((size_t)(sr >> 3) << 12) + (size_t)((sr & 7) << 9) + t]), acc);
    }
    xout[((size_t)d << 9) + t] = f2bf(fmaxf(acc, 0.f));
}

// ---------- final: per-graph mean -> logits -> softmax ----------
__global__ __launch_bounds__(512) void k_final(const u16* __restrict__ xb,
                                               const float* __restrict__ W_out,
                                               const float* __restrict__ b_out,
                                               float* __restrict__ out) {
    int g = blockIdx.x, t = threadIdx.x;
    __shared__ float mean_s[512];
    __shared__ float lg[128];
    __shared__ float red[128];
    const u16* base = xb + (size_t)g * NODESPER * HID;
    float s = 0.f;
    for (int n = 0; n < NODESPER; ++n) s += bf2f(base[(size_t)n * HID + t]);
    mean_s[t] = s * (1.0f / (float)NODESPER);
    __syncthreads();
    if (t < NOUT) {
        float a = b_out[t];
        for (int k = 0; k < HID; ++k) a = fmaf(mean_s[k], W_out[(size_t)k * NOUT + t], a);
        lg[t] = a;
        red[t] = a;
    }
    __syncthreads();
    for (int off = 64; off > 0; off >>= 1) {
        if (t < off) red[t] = fmaxf(red[t], red[t + off]);
        __syncthreads();
    }
    float mx = red[0];
    __syncthreads();
    if (t < NOUT) { float e = expf(lg[t] - mx); lg[t] = e; red[t] = e; }
    __syncthreads();
    for (int off = 64; off > 0; off >>= 1) {
        if (t < off) red[t] += red[t + off];
        __syncthreads();
    }
    if (t < NOUT) out[(size_t)g * NOUT + t] = lg[t] / red[0];
}

extern "C" void kernel_launch(void* const* d_in, const int* in_sizes, int n_in,
                              void* d_out, int out_size, void* d_ws, size_t ws_size,
                              hipStream_t stream) {
    const float* h      = (const float*)d_in[0];
    const int*   src    = (const int*)d_in[1];
    const int*   dst    = (const int*)d_in[2];
    const int*   rel    = (const int*)d_in[3];
    const float* norm   = (const float*)d_in[4];
    const float* W_elmo = (const float*)d_in[5];
    const float* b_elmo = (const float*)d_in[6];
    const float* comp   = (const float*)d_in[7];
    const float* V      = (const float*)d_in[8];
    const float* b_gcn  = (const float*)d_in[9];
    const float* W_out  = (const float*)d_in[10];
    const float* b_out  = (const float*)d_in[11];
    float* out = (float*)d_out;

    char* ws = (char*)d_ws;
    u16*   xb     = (u16*)(ws + OFF_XB);
    u16*   y      = (u16*)(ws + OFF_Y);
    u16*   hbf    = (u16*)(ws + OFF_Y);   // reuse: hbf dead once ELMo GEMM completes
    u16*   wcatT  = (u16*)(ws + OFF_WCT);
    u16*   welmoT = (u16*)(ws + OFF_WET);
    int*   cnt    = (int*)(ws + OFF_CNT);
    int*   rowptr = (int*)(ws + OFF_ROWPTR);
    int*   cursor = (int*)(ws + OFF_CURSOR);
    int*   epk    = (int*)(ws + OFF_EPK);
    float* enorm  = (float*)(ws + OFF_ENORM);

    // zero x buffer (upper 256 feature dims stay 0 for layer-1 input) and histogram
    hipMemsetAsync(xb, 0, (size_t)TOT * HID * 2, stream);
    hipMemsetAsync(cnt, 0, (size_t)TOT * 4, stream);

    k_cvt<<<2048, 256, 0, stream>>>(h, hbf);
    k_prep_wcat<<<8192, 256, 0, stream>>>(comp, V, wcatT);
    k_prep_welmo<<<3072, 256, 0, stream>>>(W_elmo, welmoT);

    k_hist<<<EDGES / 256, 256, 0, stream>>>(dst, cnt);
    k_scan<<<1, 1024, 0, stream>>>(cnt, rowptr, cursor);
    k_scatter<<<EDGES / 256, 256, 0, stream>>>(src, dst, rel, norm, cursor, epk, enorm);

    // ELMo: xb[:, 0:256] = relu(hbf @ W_elmo + b_elmo)   (M=16384, K=3072, N=256)
    k_gemm<true><<<dim3(128, 2), 256, 0, stream>>>(hbf, welmoT, xb, b_elmo, INDIM, HID);

    for (int L = 0; L < 3; ++L) {
        // y = xb @ Wcat   (M=16384, K=512, N=4096)
        k_gemm<false><<<dim3(128, 32), 256, 0, stream>>>(xb, wcatT, y, nullptr, HID,
                                                         NRELS * HID);
        // xb = relu(b_gcn + segment_sum(norm * y[src, r]))
        k_agg<<<TOT, 512, 0, stream>>>(y, rowptr, epk, enorm, b_gcn, xb);
    }

    k_final<<<NGRAPH, 512, 0, stream>>>(xb, W_out, b_out, out);
}

// Round 3
// 613.155 us; speedup vs baseline: 1.4437x; 1.2820x over previous
//
#include <hip/hip_runtime.h>

typedef unsigned short u16;
typedef unsigned int   u32;
typedef u16   u16x4 __attribute__((ext_vector_type(4)));
typedef u16   u16x8 __attribute__((ext_vector_type(8)));
typedef short s16x8 __attribute__((ext_vector_type(8)));
typedef float f32x4 __attribute__((ext_vector_type(4)));

// ---------- bf16 helpers (bit-level, RNE) ----------
__device__ __forceinline__ float bf2f(u16 u) {
    u32 x = ((u32)u) << 16;
    return __builtin_bit_cast(float, x);
}
__device__ __forceinline__ u16 f2bf(float f) {
    u32 u = __builtin_bit_cast(u32, f);
    u32 r = u + 0x7FFFu + ((u >> 16) & 1u);
    return (u16)(r >> 16);
}

// async global->LDS, 16B per lane; lds dest is wave-uniform base (HW: base + lane*16)
__device__ __forceinline__ void gload16(const u16* g, u16* lds) {
    __builtin_amdgcn_global_load_lds((const __attribute__((address_space(1))) void*)g,
                                     (__attribute__((address_space(3))) void*)lds, 16, 0, 0);
}

// ---------- sizes ----------
#define TOT   16384      // BS*N nodes
#define HID   512
#define NRELS 8
#define NB    4
#define EDGES 262144
#define INDIM 3072
#define NOUT  128
#define NGRAPH 16
#define NODESPER 1024
#define KSPLIT 3         // ELMo split-K factor (K=3072 -> 1024 per block)

// workspace layout (16B aligned)
#define OFF_XB     ((size_t)0)                    // u16 [16384][512]   16,777,216 B
#define OFF_Y      (OFF_XB + 16777216)            // u16 [16384][4096] 134,217,728 B (reused as ELMo f32 partials [3][16384][256] = 50,331,648 B)
#define OFF_WCT    (OFF_Y + 134217728)            // u16 [4096][512]     4,194,304 B
#define OFF_WET    (OFF_WCT + 4194304)            // u16 [256][3072]     1,572,864 B
#define OFF_CNT    (OFF_WET + 1572864)            // int [16384]
#define OFF_ROWPTR (OFF_CNT + 65536)              // int [16385] (+pad)
#define OFF_CURSOR (OFF_ROWPTR + 65552)           // int [16384]
#define OFF_EPK    (OFF_CURSOR + 65536)           // int [262144]
#define OFF_ENORM  (OFF_EPK + 1048576)            // float [262144]
#define OFF_PART   (OFF_ENORM + 1048576)          // float [256][512]      524,288 B

// ---------- prep: WcatT[(r*512+n)][k] = sum_b comp[r,b] * V[b][k][n]  (bf16) ----------
__global__ __launch_bounds__(256) void k_prep_wcat(const float* __restrict__ comp,
                                                   const float* __restrict__ V,
                                                   u16* __restrict__ WcatT) {
    int idx = blockIdx.x * 256 + threadIdx.x;      // 8*512*512 = 2,097,152
    int k = idx & 511;
    int n = (idx >> 9) & 511;
    int r = idx >> 18;
    float s = 0.f;
#pragma unroll
    for (int b = 0; b < NB; ++b)
        s = fmaf(comp[r * NB + b], V[((size_t)b << 18) + (size_t)k * 512 + n], s);
    WcatT[(((size_t)(r * 512 + n)) << 9) + k] = f2bf(s);
}

// ---------- prep: WelmoT[n][k] = W_elmo[k][n] (bf16) ----------
__global__ __launch_bounds__(256) void k_prep_welmo(const float* __restrict__ W,
                                                    u16* __restrict__ WT) {
    int idx = blockIdx.x * 256 + threadIdx.x;      // 256*3072 = 786,432
    int k = idx % 3072;
    int n = idx / 3072;
    WT[idx] = f2bf(W[(size_t)k * 256 + n]);
}

// ---------- CSR build ----------
__global__ __launch_bounds__(256) void k_hist(const int* __restrict__ dst, int* __restrict__ cnt) {
    int e = blockIdx.x * 256 + threadIdx.x;
    atomicAdd(&cnt[dst[e]], 1);
}

__global__ __launch_bounds__(1024) void k_scan(const int* __restrict__ cnt,
                                               int* __restrict__ rowptr,
                                               int* __restrict__ cursor) {
    __shared__ int part[1024];
    int t = threadIdx.x;
    int loc[16];
    int s = 0;
    int base = t * 16;
#pragma unroll
    for (int i = 0; i < 16; ++i) { loc[i] = s; s += cnt[base + i]; }
    part[t] = s;
    __syncthreads();
    for (int off = 1; off < 1024; off <<= 1) {
        int v = (t >= off) ? part[t - off] : 0;
        __syncthreads();
        part[t] += v;
        __syncthreads();
    }
    int excl = (t == 0) ? 0 : part[t - 1];
#pragma unroll
    for (int i = 0; i < 16; ++i) {
        int v = excl + loc[i];
        rowptr[base + i] = v;
        cursor[base + i] = v;
    }
    if (t == 1023) rowptr[TOT] = part[1023];
}

__global__ __launch_bounds__(256) void k_scatter(const int* __restrict__ src,
                                                 const int* __restrict__ dst,
                                                 const int* __restrict__ rel,
                                                 const float* __restrict__ norm,
                                                 int* __restrict__ cursor,
                                                 int* __restrict__ epk,
                                                 float* __restrict__ enorm) {
    int e = blockIdx.x * 256 + threadIdx.x;
    int d = dst[e];
    int pos = atomicAdd(&cursor[d], 1);
    epk[pos] = (src[e] << 3) | rel[e];
    enorm[pos] = norm[e];
}

// ---------- layer GEMM (m97 structure): C[M,N](bf16) = A[M,K] @ BT[N,K]^T ----------
// tile 128x128, BK=64, 256 threads (4 waves, 2x2 of 64x64 sub-tiles)
// global_load_lds width-16 staging, both-sides XOR swizzle, XCD chunk swizzle.
__global__ __launch_bounds__(256, 4) void k_gemm(const u16* __restrict__ A,
                                                 const u16* __restrict__ BT,
                                                 u16* __restrict__ C,
                                                 int K, int ldc) {
    __shared__ __align__(16) u16 As[128 * 64];
    __shared__ __align__(16) u16 Bs[128 * 64];

    const int t = threadIdx.x;
    // XCD-aware bijective chunk swizzle (nwg = 128*32 = 4096, %8 == 0)
    const int lin = blockIdx.y * 128 + blockIdx.x;
    const int swz = (lin & 7) * 512 + (lin >> 3);
    const int tileM = (swz & 127) * 128;
    const int tileN = (swz >> 7) * 128;

    const int w = t >> 6, l = t & 63;
    const int wr = w >> 1, wc = w & 1;
    const int lo = l & 15, hi = l >> 4;

    const int srow8 = l >> 3;                 // 0..7: row within 8-row staging group
    const int scol = ((l & 7) ^ srow8) * 8;   // pre-swizzled source 16B-chunk (u16 units)

    f32x4 acc[4][4];
#pragma unroll
    for (int m = 0; m < 4; ++m)
#pragma unroll
        for (int n = 0; n < 4; ++n) acc[m][n] = f32x4{0.f, 0.f, 0.f, 0.f};

    for (int k0 = 0; k0 < K; k0 += 64) {
#pragma unroll
        for (int i = 0; i < 4; ++i) {
            const int rowblk = (w * 4 + i) * 8;            // wave-uniform
            gload16(A + (size_t)(tileM + rowblk + srow8) * K + k0 + scol, &As[rowblk * 64]);
            gload16(BT + (size_t)(tileN + rowblk + srow8) * K + k0 + scol, &Bs[rowblk * 64]);
        }
        __syncthreads();

#pragma unroll
        for (int kk = 0; kk < 2; ++kk) {
            s16x8 af[4], bf[4];
#pragma unroll
            for (int m = 0; m < 4; ++m) {
                int row = wr * 64 + m * 16 + lo;
                int boff = (row * 128 + kk * 64 + hi * 16) ^ ((row & 7) << 4);
                af[m] = *(const s16x8*)((const char*)As + boff);
            }
#pragma unroll
            for (int n = 0; n < 4; ++n) {
                int row = wc * 64 + n * 16 + lo;
                int boff = (row * 128 + kk * 64 + hi * 16) ^ ((row & 7) << 4);
                bf[n] = *(const s16x8*)((const char*)Bs + boff);
            }
#pragma unroll
            for (int m = 0; m < 4; ++m)
#pragma unroll
                for (int n = 0; n < 4; ++n)
                    acc[m][n] = __builtin_amdgcn_mfma_f32_16x16x32_bf16(
                        af[m], bf[n], acc[m][n], 0, 0, 0);
        }
        __syncthreads();
    }

    // epilogue: C/D layout col=lane&15, row=(lane>>4)*4+reg
#pragma unroll
    for (int m = 0; m < 4; ++m)
#pragma unroll
        for (int n = 0; n < 4; ++n) {
            int col = tileN + wc * 64 + n * 16 + lo;
#pragma unroll
            for (int j = 0; j < 4; ++j) {
                int row = tileM + wr * 64 + m * 16 + hi * 4 + j;
                C[(size_t)row * ldc + col] = f2bf(acc[m][n][j]);
            }
        }
}

// ---------- ELMo GEMM: split-K, A in f32 (reg-staged + cvt), B via global_load_lds ----------
// grid dim3(2, 128, KSPLIT); writes f32 partials Cp[kz][16384][256]
__global__ __launch_bounds__(256, 3) void k_gemm_elmo(const float* __restrict__ A,
                                                      const u16* __restrict__ BT,
                                                      float* __restrict__ Cp) {
    __shared__ __align__(16) u16 As[128 * 64];
    __shared__ __align__(16) u16 Bs[128 * 64];

    const int t = threadIdx.x;
    const int tileN = blockIdx.x * 128;
    const int tileM = blockIdx.y * 128;
    const int kz = blockIdx.z;

    const int w = t >> 6, l = t & 63;
    const int wr = w >> 1, wc = w & 1;
    const int lo = l & 15, hi = l >> 4;

    const int srow8 = l >> 3;
    const int gc = (l & 7) ^ srow8;           // swizzled global chunk for this lane
    const int scol = gc * 8;

    f32x4 acc[4][4];
#pragma unroll
    for (int m = 0; m < 4; ++m)
#pragma unroll
        for (int n = 0; n < 4; ++n) acc[m][n] = f32x4{0.f, 0.f, 0.f, 0.f};

    const int kbeg = kz * (INDIM / KSPLIT);
    const int kend = kbeg + (INDIM / KSPLIT);
    for (int k0 = kbeg; k0 < kend; k0 += 64) {
        // A: f32 -> bf16 reg-staged, ds_write to the same swizzled layout
#pragma unroll
        for (int i = 0; i < 4; ++i) {
            const int rowblk = (w * 4 + i) * 8;
            const float* ap = A + (size_t)(tileM + rowblk + srow8) * INDIM + k0 + scol;
            f32x4 v0 = *(const f32x4*)ap;
            f32x4 v1 = *(const f32x4*)(ap + 4);
            u16x8 wv;
#pragma unroll
            for (int j = 0; j < 4; ++j) { wv[j] = f2bf(v0[j]); wv[j + 4] = f2bf(v1[j]); }
            *(u16x8*)&As[(rowblk + srow8) * 64 + (l & 7) * 8] = wv;
            // B: async direct-to-LDS
            gload16(BT + (size_t)(tileN + rowblk + srow8) * INDIM + k0 + scol, &Bs[rowblk * 64]);
        }
        __syncthreads();

#pragma unroll
        for (int kk = 0; kk < 2; ++kk) {
            s16x8 af[4], bf[4];
#pragma unroll
            for (int m = 0; m < 4; ++m) {
                int row = wr * 64 + m * 16 + lo;
                int boff = (row * 128 + kk * 64 + hi * 16) ^ ((row & 7) << 4);
                af[m] = *(const s16x8*)((const char*)As + boff);
            }
#pragma unroll
            for (int n = 0; n < 4; ++n) {
                int row = wc * 64 + n * 16 + lo;
                int boff = (row * 128 + kk * 64 + hi * 16) ^ ((row & 7) << 4);
                bf[n] = *(const s16x8*)((const char*)Bs + boff);
            }
#pragma unroll
            for (int m = 0; m < 4; ++m)
#pragma unroll
                for (int n = 0; n < 4; ++n)
                    acc[m][n] = __builtin_amdgcn_mfma_f32_16x16x32_bf16(
                        af[m], bf[n], acc[m][n], 0, 0, 0);
        }
        __syncthreads();
    }

    float* cp = Cp + (size_t)kz * TOT * 256;
#pragma unroll
    for (int m = 0; m < 4; ++m)
#pragma unroll
        for (int n = 0; n < 4; ++n) {
            int col = tileN + wc * 64 + n * 16 + lo;
#pragma unroll
            for (int j = 0; j < 4; ++j) {
                int row = tileM + wr * 64 + m * 16 + hi * 4 + j;
                cp[(size_t)row * 256 + col] = acc[m][n][j];
            }
        }
}

// ---------- ELMo reduce: xb[:, 0:256] = relu(sum_kz Cp + bias) ----------
__global__ __launch_bounds__(256) void k_elmo_reduce(const float* __restrict__ Cp,
                                                     const float* __restrict__ bias,
                                                     u16* __restrict__ xb) {
    int idx = blockIdx.x * 256 + threadIdx.x;   // 16384*256/4 = 1,048,576
    int row = idx >> 6;
    int c4 = (idx & 63) * 4;
    f32x4 s = *(const f32x4*)(Cp + (size_t)row * 256 + c4);
#pragma unroll
    for (int p = 1; p < KSPLIT; ++p)
        s += *(const f32x4*)(Cp + (size_t)p * TOT * 256 + (size_t)row * 256 + c4);
    f32x4 bv = *(const f32x4*)(bias + c4);
    u16x4 o;
#pragma unroll
    for (int j = 0; j < 4; ++j) o[j] = f2bf(fmaxf(s[j] + bv[j], 0.f));
    *(u16x4*)(xb + (size_t)row * HID + c4) = o;
}

// ---------- aggregation: x_new[d] = relu(b + sum_e norm_e * y[src_e, r_e*512 + :]) ----------
// 256 threads, 2 features/thread (u32 loads), edge meta staged in LDS, unroll x4
__global__ __launch_bounds__(256) void k_agg(const u16* __restrict__ y,
                                             const int* __restrict__ rowptr,
                                             const int* __restrict__ epk,
                                             const float* __restrict__ enorm,
                                             const float* __restrict__ bgcn,
                                             u16* __restrict__ xout) {
    __shared__ int   s_epk[64];
    __shared__ float s_nrm[64];
    const int d = blockIdx.x, t = threadIdx.x;
    const u32* yw = (const u32*)y;

    float2 bv = *(const float2*)(bgcn + 2 * t);
    float a0 = bv.x, a1 = bv.y;

    const int beg = rowptr[d], end = rowptr[d + 1];
    for (int base = beg; base < end; base += 64) {
        const int m = min(64, end - base);
        if (t < m) { s_epk[t] = epk[base + t]; s_nrm[t] = enorm[base + t]; }
        __syncthreads();
        int c = 0;
        for (; c + 4 <= m; c += 4) {
            int   k0 = s_epk[c],     k1 = s_epk[c + 1],  k2 = s_epk[c + 2],  k3 = s_epk[c + 3];
            float n0 = s_nrm[c],     n1 = s_nrm[c + 1],  n2 = s_nrm[c + 2],  n3 = s_nrm[c + 3];
            u32 w0 = yw[((size_t)(k0 >> 3) << 11) + ((k0 & 7) << 8) + t];
            u32 w1 = yw[((size_t)(k1 >> 3) << 11) + ((k1 & 7) << 8) + t];
            u32 w2 = yw[((size_t)(k2 >> 3) << 11) + ((k2 & 7) << 8) + t];
            u32 w3 = yw[((size_t)(k3 >> 3) << 11) + ((k3 & 7) << 8) + t];
            a0 = fmaf(n0, bf2f((u16)w0), a0); a1 = fmaf(n0, bf2f((u16)(w0 >> 16)), a1);
            a0 = fmaf(n1, bf2f((u16)w1), a0); a1 = fmaf(n1, bf2f((u16)(w1 >> 16)), a1);
            a0 = fmaf(n2, bf2f((u16)w2), a0); a1 = fmaf(n2, bf2f((u16)(w2 >> 16)), a1);
            a0 = fmaf(n3, bf2f((u16)w3), a0); a1 = fmaf(n3, bf2f((u16)(w3 >> 16)), a1);
        }
        for (; c < m; ++c) {
            int k0 = s_epk[c];
            float n0 = s_nrm[c];
            u32 w0 = yw[((size_t)(k0 >> 3) << 11) + ((k0 & 7) << 8) + t];
            a0 = fmaf(n0, bf2f((u16)w0), a0); a1 = fmaf(n0, bf2f((u16)(w0 >> 16)), a1);
        }
        __syncthreads();
    }
    u32 o = (u32)f2bf(fmaxf(a0, 0.f)) | ((u32)f2bf(fmaxf(a1, 0.f)) << 16);
    ((u32*)xout)[((size_t)d << 8) + t] = o;
}

// ---------- final stage 1: per-(graph, 64-node chunk) feature sums ----------
__global__ __launch_bounds__(512) void k_mean1(const u16* __restrict__ xb,
                                               float* __restrict__ part) {
    int g = blockIdx.x >> 4, chunk = blockIdx.x & 15, t = threadIdx.x;
    const u16* base = xb + ((size_t)g * NODESPER + chunk * 64) * HID;
    float s = 0.f;
    for (int n = 0; n < 64; ++n) s += bf2f(base[(size_t)n * HID + t]);
    part[(size_t)blockIdx.x * HID + t] = s;
}

// ---------- final stage 2: reduce partials -> mean -> logits -> softmax ----------
__global__ __launch_bounds__(512) void k_final2(const float* __restrict__ part,
                                                const float* __restrict__ W_out,
                                                const float* __restrict__ b_out,
                                                float* __restrict__ out) {
    int g = blockIdx.x, t = threadIdx.x;
    __shared__ float mean_s[512];
    __shared__ float lg[128];
    __shared__ float red[128];
    float s = 0.f;
#pragma unroll
    for (int c = 0; c < 16; ++c) s += part[((size_t)g * 16 + c) * HID + t];
    mean_s[t] = s * (1.0f / (float)NODESPER);
    __syncthreads();
    if (t < NOUT) {
        float a = b_out[t];
        for (int k = 0; k < HID; ++k) a = fmaf(mean_s[k], W_out[(size_t)k * NOUT + t], a);
        lg[t] = a;
        red[t] = a;
    }
    __syncthreads();
    for (int off = 64; off > 0; off >>= 1) {
        if (t < off) red[t] = fmaxf(red[t], red[t + off]);
        __syncthreads();
    }
    float mx = red[0];
    __syncthreads();
    if (t < NOUT) { float e = expf(lg[t] - mx); lg[t] = e; red[t] = e; }
    __syncthreads();
    for (int off = 64; off > 0; off >>= 1) {
        if (t < off) red[t] += red[t + off];
        __syncthreads();
    }
    if (t < NOUT) out[(size_t)g * NOUT + t] = lg[t] / red[0];
}

extern "C" void kernel_launch(void* const* d_in, const int* in_sizes, int n_in,
                              void* d_out, int out_size, void* d_ws, size_t ws_size,
                              hipStream_t stream) {
    const float* h      = (const float*)d_in[0];
    const int*   src    = (const int*)d_in[1];
    const int*   dst    = (const int*)d_in[2];
    const int*   rel    = (const int*)d_in[3];
    const float* norm   = (const float*)d_in[4];
    const float* W_elmo = (const float*)d_in[5];
    const float* b_elmo = (const float*)d_in[6];
    const float* comp   = (const float*)d_in[7];
    const float* V      = (const float*)d_in[8];
    const float* b_gcn  = (const float*)d_in[9];
    const float* W_out  = (const float*)d_in[10];
    const float* b_out  = (const float*)d_in[11];
    float* out = (float*)d_out;

    char* ws = (char*)d_ws;
    u16*   xb     = (u16*)(ws + OFF_XB);
    u16*   y      = (u16*)(ws + OFF_Y);
    float* elmoP  = (float*)(ws + OFF_Y);  // reuse: dead once ELMo reduce completes
    u16*   wcatT  = (u16*)(ws + OFF_WCT);
    u16*   welmoT = (u16*)(ws + OFF_WET);
    int*   cnt    = (int*)(ws + OFF_CNT);
    int*   rowptr = (int*)(ws + OFF_ROWPTR);
    int*   cursor = (int*)(ws + OFF_CURSOR);
    int*   epk    = (int*)(ws + OFF_EPK);
    float* enorm  = (float*)(ws + OFF_ENORM);
    float* part   = (float*)(ws + OFF_PART);

    // zero x buffer (upper 256 feature dims stay 0 for layer-1 input) and histogram
    hipMemsetAsync(xb, 0, (size_t)TOT * HID * 2, stream);
    hipMemsetAsync(cnt, 0, (size_t)TOT * 4, stream);

    k_prep_wcat<<<8192, 256, 0, stream>>>(comp, V, wcatT);
    k_prep_welmo<<<3072, 256, 0, stream>>>(W_elmo, welmoT);

    k_hist<<<EDGES / 256, 256, 0, stream>>>(dst, cnt);
    k_scan<<<1, 1024, 0, stream>>>(cnt, rowptr, cursor);
    k_scatter<<<EDGES / 256, 256, 0, stream>>>(src, dst, rel, norm, cursor, epk, enorm);

    // ELMo: xb[:, 0:256] = relu(h @ W_elmo + b_elmo)  (M=16384, K=3072 split x3, N=256)
    k_gemm_elmo<<<dim3(2, 128, KSPLIT), 256, 0, stream>>>(h, welmoT, elmoP);
    k_elmo_reduce<<<4096, 256, 0, stream>>>(elmoP, b_elmo, xb);

    for (int L = 0; L < 3; ++L) {
        // y = xb @ Wcat   (M=16384, K=512, N=4096)
        k_gemm<<<dim3(128, 32), 256, 0, stream>>>(xb, wcatT, y, HID, NRELS * HID);
        // xb = relu(b_gcn + segment_sum(norm * y[src, r]))
        k_agg<<<TOT, 256, 0, stream>>>(y, rowptr, epk, enorm, b_gcn, xb);
    }

    k_mean1<<<NGRAPH * 16, 512, 0, stream>>>(xb, part);
    k_final2<<<NGRAPH, 512, 0, stream>>>(part, W_out, b_out, out);
}

// Round 4
// 611.349 us; speedup vs baseline: 1.4480x; 1.0030x over previous
//
#include <hip/hip_runtime.h>

typedef unsigned short u16;
typedef unsigned int   u32;
typedef u16   u16x4 __attribute__((ext_vector_type(4)));
typedef u16   u16x8 __attribute__((ext_vector_type(8)));
typedef short s16x8 __attribute__((ext_vector_type(8)));
typedef float f32x4 __attribute__((ext_vector_type(4)));

// ---------- bf16 helpers (bit-level, RNE) ----------
__device__ __forceinline__ float bf2f(u16 u) {
    u32 x = ((u32)u) << 16;
    return __builtin_bit_cast(float, x);
}
__device__ __forceinline__ u16 f2bf(float f) {
    u32 u = __builtin_bit_cast(u32, f);
    u32 r = u + 0x7FFFu + ((u >> 16) & 1u);
    return (u16)(r >> 16);
}

// async global->LDS, 16B per lane; lds dest is wave-uniform base (HW: base + lane*16)
__device__ __forceinline__ void gload16(const u16* g, u16* lds) {
    __builtin_amdgcn_global_load_lds((const __attribute__((address_space(1))) void*)g,
                                     (__attribute__((address_space(3))) void*)lds, 16, 0, 0);
}

// ---------- sizes ----------
#define TOT   16384      // BS*N nodes
#define HID   512
#define NRELS 8
#define NB    4
#define EDGES 262144
#define INDIM 3072
#define NOUT  128
#define NGRAPH 16
#define NODESPER 1024
#define KSPLIT 4         // ELMo split-K factor (K=3072 -> 768 per block, 12 k-steps)

// workspace layout (16B aligned)
#define OFF_XB     ((size_t)0)                    // u16 [16384][512]   16,777,216 B
#define OFF_Y      (OFF_XB + 16777216)            // u16 [16384][4096] 134,217,728 B (reused as ELMo f32 partials [4][16384][256] = 67,108,864 B)
#define OFF_WCT    (OFF_Y + 134217728)            // u16 [4096][512]     4,194,304 B
#define OFF_WET    (OFF_WCT + 4194304)            // u16 [256][3072]     1,572,864 B
#define OFF_CNT    (OFF_WET + 1572864)            // int [16384]
#define OFF_ROWPTR (OFF_CNT + 65536)              // int [16385] (+pad)
#define OFF_CURSOR (OFF_ROWPTR + 65552)           // int [16384]
#define OFF_EPK    (OFF_CURSOR + 65536)           // int [262144]
#define OFF_ENORM  (OFF_EPK + 1048576)            // float [262144]
#define OFF_PART   (OFF_ENORM + 1048576)          // float [256][512]      524,288 B

// ---------- prep: WcatT[(r*512+n)][k] = sum_b comp[r,b] * V[b][k][n]  (LDS transpose) ----------
__global__ __launch_bounds__(256) void k_prep_wcat(const float* __restrict__ comp,
                                                   const float* __restrict__ V,
                                                   u16* __restrict__ WcatT) {
    __shared__ float tile[64][65];
    const int r = blockIdx.z, k0 = blockIdx.x * 64, n0 = blockIdx.y * 64;
    const float c0 = comp[r * 4], c1 = comp[r * 4 + 1], c2 = comp[r * 4 + 2], c3 = comp[r * 4 + 3];
    const int tn = threadIdx.x & 63;   // n fast -> coalesced V reads
    const int tk = threadIdx.x >> 6;
#pragma unroll
    for (int i = 0; i < 16; ++i) {
        int k = tk + i * 4;
        const float* vp = V + (size_t)(k0 + k) * 512 + n0 + tn;
        float s = c0 * vp[0] + c1 * vp[262144] + c2 * vp[2 * 262144] + c3 * vp[3 * 262144];
        tile[k][tn] = s;
    }
    __syncthreads();
    const int kk = threadIdx.x & 63;   // k fast -> coalesced WcatT writes
    const int nn = threadIdx.x >> 6;
#pragma unroll
    for (int i = 0; i < 16; ++i) {
        int n = nn + i * 4;
        WcatT[((size_t)(r * 512 + n0 + n) << 9) + k0 + kk] = f2bf(tile[kk][n]);
    }
}

// ---------- prep: WelmoT[n][k] = W_elmo[k][n] (LDS transpose) ----------
__global__ __launch_bounds__(256) void k_prep_welmo(const float* __restrict__ W,
                                                    u16* __restrict__ WT) {
    __shared__ float tile[64][65];
    const int k0 = blockIdx.x * 64, n0 = blockIdx.y * 64;
    const int tn = threadIdx.x & 63;
    const int tk = threadIdx.x >> 6;
#pragma unroll
    for (int i = 0; i < 16; ++i) {
        int k = tk + i * 4;
        tile[k][tn] = W[(size_t)(k0 + k) * 256 + n0 + tn];
    }
    __syncthreads();
    const int kk = threadIdx.x & 63;
    const int nn = threadIdx.x >> 6;
#pragma unroll
    for (int i = 0; i < 16; ++i) {
        int n = nn + i * 4;
        WT[(size_t)(n0 + n) * 3072 + k0 + kk] = f2bf(tile[kk][n]);
    }
}

// ---------- CSR build ----------
__global__ __launch_bounds__(256) void k_hist(const int* __restrict__ dst, int* __restrict__ cnt) {
    int e = blockIdx.x * 256 + threadIdx.x;
    atomicAdd(&cnt[dst[e]], 1);
}

__global__ __launch_bounds__(1024) void k_scan(const int* __restrict__ cnt,
                                               int* __restrict__ rowptr,
                                               int* __restrict__ cursor) {
    __shared__ int part[1024];
    int t = threadIdx.x;
    int loc[16];
    int s = 0;
    int base = t * 16;
#pragma unroll
    for (int i = 0; i < 16; ++i) { loc[i] = s; s += cnt[base + i]; }
    part[t] = s;
    __syncthreads();
    for (int off = 1; off < 1024; off <<= 1) {
        int v = (t >= off) ? part[t - off] : 0;
        __syncthreads();
        part[t] += v;
        __syncthreads();
    }
    int excl = (t == 0) ? 0 : part[t - 1];
#pragma unroll
    for (int i = 0; i < 16; ++i) {
        int v = excl + loc[i];
        rowptr[base + i] = v;
        cursor[base + i] = v;
    }
    if (t == 1023) rowptr[TOT] = part[1023];
}

__global__ __launch_bounds__(256) void k_scatter(const int* __restrict__ src,
                                                 const int* __restrict__ dst,
                                                 const int* __restrict__ rel,
                                                 const float* __restrict__ norm,
                                                 int* __restrict__ cursor,
                                                 int* __restrict__ epk,
                                                 float* __restrict__ enorm) {
    int e = blockIdx.x * 256 + threadIdx.x;
    int d = dst[e];
    int pos = atomicAdd(&cursor[d], 1);
    epk[pos] = (src[e] << 3) | rel[e];
    enorm[pos] = norm[e];
}

// ---------- layer GEMM: 2-phase double-buffered (T3 minimum recipe) ----------
// tile 128x128, BK=64, 256 threads; LDS 2x(16+16) KB; global_load_lds staging with
// both-sides XOR swizzle; per-step: {sync; STAGE(next)->buf^1; fragread+MFMA(cur)}
__global__ __launch_bounds__(256, 2) void k_gemm(const u16* __restrict__ A,
                                                 const u16* __restrict__ BT,
                                                 u16* __restrict__ C,
                                                 int K, int ldc) {
    __shared__ __align__(16) u16 As[2][128 * 64];
    __shared__ __align__(16) u16 Bs[2][128 * 64];

    const int t = threadIdx.x;
    // XCD-aware bijective chunk swizzle (nwg = 4096, %8 == 0)
    const int lin = blockIdx.y * 128 + blockIdx.x;
    const int swz = (lin & 7) * 512 + (lin >> 3);
    const int tileM = (swz & 127) * 128;
    const int tileN = (swz >> 7) * 128;

    const int w = t >> 6, l = t & 63;
    const int wr = w >> 1, wc = w & 1;
    const int lo = l & 15, hi = l >> 4;

    const int srow8 = l >> 3;
    const int scol = ((l & 7) ^ srow8) * 8;   // pre-swizzled source chunk

    f32x4 acc[4][4];
#pragma unroll
    for (int m = 0; m < 4; ++m)
#pragma unroll
        for (int n = 0; n < 4; ++n) acc[m][n] = f32x4{0.f, 0.f, 0.f, 0.f};

    const int nt = K >> 6;

    // prologue: stage tile 0 into buf 0
#pragma unroll
    for (int i = 0; i < 4; ++i) {
        const int rowblk = (w * 4 + i) * 8;
        gload16(A + (size_t)(tileM + rowblk + srow8) * K + scol, &As[0][rowblk * 64]);
        gload16(BT + (size_t)(tileN + rowblk + srow8) * K + scol, &Bs[0][rowblk * 64]);
    }

    int cur = 0;
    for (int tt = 0; tt < nt; ++tt) {
        __syncthreads();   // drains staging of buf[cur]; protects buf[cur^1] re-staging

        if (tt + 1 < nt) {
            const int k0 = (tt + 1) << 6;
#pragma unroll
            for (int i = 0; i < 4; ++i) {
                const int rowblk = (w * 4 + i) * 8;
                gload16(A + (size_t)(tileM + rowblk + srow8) * K + k0 + scol,
                        &As[cur ^ 1][rowblk * 64]);
                gload16(BT + (size_t)(tileN + rowblk + srow8) * K + k0 + scol,
                        &Bs[cur ^ 1][rowblk * 64]);
            }
        }

        const char* Ab = (const char*)&As[cur][0];
        const char* Bb = (const char*)&Bs[cur][0];
#pragma unroll
        for (int kk = 0; kk < 2; ++kk) {
            s16x8 af[4], bf[4];
#pragma unroll
            for (int m = 0; m < 4; ++m) {
                int row = wr * 64 + m * 16 + lo;
                int boff = (row * 128 + kk * 64 + hi * 16) ^ ((row & 7) << 4);
                af[m] = *(const s16x8*)(Ab + boff);
            }
#pragma unroll
            for (int n = 0; n < 4; ++n) {
                int row = wc * 64 + n * 16 + lo;
                int boff = (row * 128 + kk * 64 + hi * 16) ^ ((row & 7) << 4);
                bf[n] = *(const s16x8*)(Bb + boff);
            }
#pragma unroll
            for (int m = 0; m < 4; ++m)
#pragma unroll
                for (int n = 0; n < 4; ++n)
                    acc[m][n] = __builtin_amdgcn_mfma_f32_16x16x32_bf16(
                        af[m], bf[n], acc[m][n], 0, 0, 0);
        }
        cur ^= 1;
    }

    // epilogue: C/D layout col=lane&15, row=(lane>>4)*4+reg
#pragma unroll
    for (int m = 0; m < 4; ++m)
#pragma unroll
        for (int n = 0; n < 4; ++n) {
            int col = tileN + wc * 64 + n * 16 + lo;
#pragma unroll
            for (int j = 0; j < 4; ++j) {
                int row = tileM + wr * 64 + m * 16 + hi * 4 + j;
                C[(size_t)row * ldc + col] = f2bf(acc[m][n][j]);
            }
        }
}

// ---------- ELMo GEMM: split-K, reg-staged f32 A (double reg buf) + dbuf LDS, pipelined ----------
// grid dim3(2, 128, KSPLIT); writes f32 partials Cp[kz][16384][256]
__global__ __launch_bounds__(256) void k_gemm_elmo(const float* __restrict__ A,
                                                   const u16* __restrict__ BT,
                                                   float* __restrict__ Cp) {
    __shared__ __align__(16) u16 As0[128 * 64], As1[128 * 64];
    __shared__ __align__(16) u16 Bs0[128 * 64], Bs1[128 * 64];

    const int t = threadIdx.x;
    const int tileN = blockIdx.x * 128;
    const int tileM = blockIdx.y * 128;
    const int kz = blockIdx.z;

    const int w = t >> 6, l = t & 63;
    const int wr = w >> 1, wc = w & 1;
    const int lo = l & 15, hi = l >> 4;

    const int srow8 = l >> 3;
    const int scol = ((l & 7) ^ srow8) * 8;   // swizzled global chunk
    const int ldsoff = (l & 7) * 8;           // linear LDS chunk (read applies XOR)

    f32x4 acc[4][4];
#pragma unroll
    for (int m = 0; m < 4; ++m)
#pragma unroll
        for (int n = 0; n < 4; ++n) acc[m][n] = f32x4{0.f, 0.f, 0.f, 0.f};

    const int kbeg = kz * (INDIM / KSPLIT);   // 768 per split, 12 k-steps

    f32x4 a0[8], a1[8];

#define LOADA(dstreg, kofs)                                                           \
    {                                                                                 \
        _Pragma("unroll") for (int i = 0; i < 4; ++i) {                               \
            const float* ap =                                                         \
                A + (size_t)(tileM + (w * 4 + i) * 8 + srow8) * INDIM + (kofs) + scol;\
            dstreg[i * 2] = *(const f32x4*)ap;                                        \
            dstreg[i * 2 + 1] = *(const f32x4*)(ap + 4);                              \
        }                                                                             \
    }
#define WRITEA(srcreg, lds)                                                           \
    {                                                                                 \
        _Pragma("unroll") for (int i = 0; i < 4; ++i) {                               \
            u16x8 wv;                                                                 \
            _Pragma("unroll") for (int j = 0; j < 4; ++j) {                           \
                wv[j] = f2bf(srcreg[i * 2][j]);                                       \
                wv[j + 4] = f2bf(srcreg[i * 2 + 1][j]);                               \
            }                                                                         \
            *(u16x8*)&lds[((w * 4 + i) * 8 + srow8) * 64 + ldsoff] = wv;              \
        }                                                                             \
    }
#define LOADB(lds, kofs)                                                              \
    {                                                                                 \
        _Pragma("unroll") for (int i = 0; i < 4; ++i) {                               \
            const int rowblk = (w * 4 + i) * 8;                                       \
            gload16(BT + (size_t)(tileN + rowblk + srow8) * INDIM + (kofs) + scol,    \
                    &lds[rowblk * 64]);                                               \
        }                                                                             \
    }
#define DOMFMA(Alds, Blds)                                                            \
    {                                                                                 \
        const char* Ab = (const char*)&Alds[0];                                       \
        const char* Bb = (const char*)&Blds[0];                                       \
        _Pragma("unroll") for (int kk = 0; kk < 2; ++kk) {                            \
            s16x8 af[4], bf[4];                                                       \
            _Pragma("unroll") for (int m = 0; m < 4; ++m) {                           \
                int row = wr * 64 + m * 16 + lo;                                      \
                int boff = (row * 128 + kk * 64 + hi * 16) ^ ((row & 7) << 4);        \
                af[m] = *(const s16x8*)(Ab + boff);                                   \
            }                                                                         \
            _Pragma("unroll") for (int n = 0; n < 4; ++n) {                           \
                int row = wc * 64 + n * 16 + lo;                                      \
                int boff = (row * 128 + kk * 64 + hi * 16) ^ ((row & 7) << 4);        \
                bf[n] = *(const s16x8*)(Bb + boff);                                   \
            }                                                                         \
            _Pragma("unroll") for (int m = 0; m < 4; ++m)                             \
                _Pragma("unroll") for (int n = 0; n < 4; ++n)                         \
                    acc[m][n] = __builtin_amdgcn_mfma_f32_16x16x32_bf16(              \
                        af[m], bf[n], acc[m][n], 0, 0, 0);                            \
        }                                                                             \
    }

    // prologue
    LOADA(a0, kbeg);
    LOADB(Bs0, kbeg);

    const int NT2 = (INDIM / KSPLIT) / 128;   // 6 double-steps
    for (int t2 = 0; t2 < NT2; ++t2) {
        const int ke = kbeg + t2 * 128;
        // even step: compute (As0,Bs0), prefetch k=ke+64 into (a1,Bs1)
        WRITEA(a0, As0);
        __syncthreads();
        LOADA(a1, ke + 64);
        LOADB(Bs1, ke + 64);
        DOMFMA(As0, Bs0);
        // odd step: compute (As1,Bs1), prefetch k=ke+128 into (a0,Bs0)
        WRITEA(a1, As1);
        __syncthreads();
        if (t2 + 1 < NT2) {
            LOADA(a0, ke + 128);
            LOADB(Bs0, ke + 128);
        }
        DOMFMA(As1, Bs1);
    }
#undef LOADA
#undef WRITEA
#undef LOADB
#undef DOMFMA

    float* cp = Cp + (size_t)kz * TOT * 256;
#pragma unroll
    for (int m = 0; m < 4; ++m)
#pragma unroll
        for (int n = 0; n < 4; ++n) {
            int col = tileN + wc * 64 + n * 16 + lo;
#pragma unroll
            for (int j = 0; j < 4; ++j) {
                int row = tileM + wr * 64 + m * 16 + hi * 4 + j;
                cp[(size_t)row * 256 + col] = acc[m][n][j];
            }
        }
}

// ---------- ELMo reduce: xb[:, 0:256] = relu(sum_kz Cp + bias) ----------
__global__ __launch_bounds__(256) void k_elmo_reduce(const float* __restrict__ Cp,
                                                     const float* __restrict__ bias,
                                                     u16* __restrict__ xb) {
    int idx = blockIdx.x * 256 + threadIdx.x;   // 16384*256/4 = 1,048,576
    int row = idx >> 6;
    int c4 = (idx & 63) * 4;
    f32x4 s = *(const f32x4*)(Cp + (size_t)row * 256 + c4);
#pragma unroll
    for (int p = 1; p < KSPLIT; ++p)
        s += *(const f32x4*)(Cp + (size_t)p * TOT * 256 + (size_t)row * 256 + c4);
    f32x4 bv = *(const f32x4*)(bias + c4);
    u16x4 o;
#pragma unroll
    for (int j = 0; j < 4; ++j) o[j] = f2bf(fmaxf(s[j] + bv[j], 0.f));
    *(u16x4*)(xb + (size_t)row * HID + c4) = o;
}

// ---------- aggregation: x_new[d] = relu(b + sum_e norm_e * y[src_e, r_e*512 + :]) ----------
// 256 threads, 2 features/thread (u32 loads), edge meta in LDS, unroll x8
__global__ __launch_bounds__(256) void k_agg(const u16* __restrict__ y,
                                             const int* __restrict__ rowptr,
                                             const int* __restrict__ epk,
                                             const float* __restrict__ enorm,
                                             const float* __restrict__ bgcn,
                                             u16* __restrict__ xout) {
    __shared__ int   s_epk[64];
    __shared__ float s_nrm[64];
    const int d = blockIdx.x, t = threadIdx.x;
    const u32* yw = (const u32*)y;

    float2 bv = *(const float2*)(bgcn + 2 * t);
    float a0 = bv.x, a1 = bv.y;

    const int beg = rowptr[d], end = rowptr[d + 1];
    for (int base = beg; base < end; base += 64) {
        const int m = min(64, end - base);
        if (t < m) { s_epk[t] = epk[base + t]; s_nrm[t] = enorm[base + t]; }
        __syncthreads();
        int c = 0;
        for (; c + 8 <= m; c += 8) {
            u32 wv[8];
            float nv[8];
#pragma unroll
            for (int q = 0; q < 8; ++q) {
                int k = s_epk[c + q];
                nv[q] = s_nrm[c + q];
                wv[q] = yw[((size_t)(k >> 3) << 11) + ((k & 7) << 8) + t];
            }
#pragma unroll
            for (int q = 0; q < 8; ++q) {
                a0 = fmaf(nv[q], bf2f((u16)wv[q]), a0);
                a1 = fmaf(nv[q], bf2f((u16)(wv[q] >> 16)), a1);
            }
        }
        for (; c < m; ++c) {
            int k0 = s_epk[c];
            float n0 = s_nrm[c];
            u32 w0 = yw[((size_t)(k0 >> 3) << 11) + ((k0 & 7) << 8) + t];
            a0 = fmaf(n0, bf2f((u16)w0), a0);
            a1 = fmaf(n0, bf2f((u16)(w0 >> 16)), a1);
        }
        __syncthreads();
    }
    u32 o = (u32)f2bf(fmaxf(a0, 0.f)) | ((u32)f2bf(fmaxf(a1, 0.f)) << 16);
    ((u32*)xout)[((size_t)d << 8) + t] = o;
}

// ---------- final stage 1: per-(graph, 64-node chunk) feature sums ----------
__global__ __launch_bounds__(512) void k_mean1(const u16* __restrict__ xb,
                                               float* __restrict__ part) {
    int g = blockIdx.x >> 4, chunk = blockIdx.x & 15, t = threadIdx.x;
    const u16* base = xb + ((size_t)g * NODESPER + chunk * 64) * HID;
    float s = 0.f;
    for (int n = 0; n < 64; ++n) s += bf2f(base[(size_t)n * HID + t]);
    part[(size_t)blockIdx.x * HID + t] = s;
}

// ---------- final stage 2: reduce partials -> mean -> logits -> softmax ----------
__global__ __launch_bounds__(512) void k_final2(const float* __restrict__ part,
                                                const float* __restrict__ W_out,
                                                const float* __restrict__ b_out,
                                                float* __restrict__ out) {
    int g = blockIdx.x, t = threadIdx.x;
    __shared__ float mean_s[512];
    __shared__ float lg[128];
    __shared__ float red[128];
    float s = 0.f;
#pragma unroll
    for (int c = 0; c < 16; ++c) s += part[((size_t)g * 16 + c) * HID + t];
    mean_s[t] = s * (1.0f / (float)NODESPER);
    __syncthreads();
    if (t < NOUT) {
        float a = b_out[t];
        for (int k = 0; k < HID; ++k) a = fmaf(mean_s[k], W_out[(size_t)k * NOUT + t], a);
        lg[t] = a;
        red[t] = a;
    }
    __syncthreads();
    for (int off = 64; off > 0; off >>= 1) {
        if (t < off) red[t] = fmaxf(red[t], red[t + off]);
        __syncthreads();
    }
    float mx = red[0];
    __syncthreads();
    if (t < NOUT) { float e = expf(lg[t] - mx); lg[t] = e; red[t] = e; }
    __syncthreads();
    for (int off = 64; off > 0; off >>= 1) {
        if (t < off) red[t] += red[t + off];
        __syncthreads();
    }
    if (t < NOUT) out[(size_t)g * NOUT + t] = lg[t] / red[0];
}

extern "C" void kernel_launch(void* const* d_in, const int* in_sizes, int n_in,
                              void* d_out, int out_size, void* d_ws, size_t ws_size,
                              hipStream_t stream) {
    const float* h      = (const float*)d_in[0];
    const int*   src    = (const int*)d_in[1];
    const int*   dst    = (const int*)d_in[2];
    const int*   rel    = (const int*)d_in[3];
    const float* norm   = (const float*)d_in[4];
    const float* W_elmo = (const float*)d_in[5];
    const float* b_elmo = (const float*)d_in[6];
    const float* comp   = (const float*)d_in[7];
    const float* V      = (const float*)d_in[8];
    const float* b_gcn  = (const float*)d_in[9];
    const float* W_out  = (const float*)d_in[10];
    const float* b_out  = (const float*)d_in[11];
    float* out = (float*)d_out;

    char* ws = (char*)d_ws;
    u16*   xb     = (u16*)(ws + OFF_XB);
    u16*   y      = (u16*)(ws + OFF_Y);
    float* elmoP  = (float*)(ws + OFF_Y);  // reuse: dead once ELMo reduce completes
    u16*   wcatT  = (u16*)(ws + OFF_WCT);
    u16*   welmoT = (u16*)(ws + OFF_WET);
    int*   cnt    = (int*)(ws + OFF_CNT);
    int*   rowptr = (int*)(ws + OFF_ROWPTR);
    int*   cursor = (int*)(ws + OFF_CURSOR);
    int*   epk    = (int*)(ws + OFF_EPK);
    float* enorm  = (float*)(ws + OFF_ENORM);
    float* part   = (float*)(ws + OFF_PART);

    // zero x buffer (upper 256 feature dims stay 0 for layer-1 input) and histogram
    hipMemsetAsync(xb, 0, (size_t)TOT * HID * 2, stream);
    hipMemsetAsync(cnt, 0, (size_t)TOT * 4, stream);

    k_prep_wcat<<<dim3(8, 8, 8), 256, 0, stream>>>(comp, V, wcatT);
    k_prep_welmo<<<dim3(48, 4), 256, 0, stream>>>(W_elmo, welmoT);

    k_hist<<<EDGES / 256, 256, 0, stream>>>(dst, cnt);
    k_scan<<<1, 1024, 0, stream>>>(cnt, rowptr, cursor);
    k_scatter<<<EDGES / 256, 256, 0, stream>>>(src, dst, rel, norm, cursor, epk, enorm);

    // ELMo: xb[:, 0:256] = relu(h @ W_elmo + b_elmo)  (M=16384, K=3072 split x4, N=256)
    k_gemm_elmo<<<dim3(2, 128, KSPLIT), 256, 0, stream>>>(h, welmoT, elmoP);
    k_elmo_reduce<<<4096, 256, 0, stream>>>(elmoP, b_elmo, xb);

    for (int L = 0; L < 3; ++L) {
        // y = xb @ Wcat   (M=16384, K=512, N=4096)
        k_gemm<<<dim3(128, 32), 256, 0, stream>>>(xb, wcatT, y, HID, NRELS * HID);
        // xb = relu(b_gcn + segment_sum(norm * y[src, r]))
        k_agg<<<TOT, 256, 0, stream>>>(y, rowptr, epk, enorm, b_gcn, xb);
    }

    k_mean1<<<NGRAPH * 16, 512, 0, stream>>>(xb, part);
    k_final2<<<NGRAPH, 512, 0, stream>>>(part, W_out, b_out, out);
}